// Round 7
// baseline (255.103 us; speedup 1.0000x reference)
//
#include <hip/hip_runtime.h>
#include <math.h>

#define Bb  64
#define Tt  256
#define Cc  384
#define NHh 6
#define HDd 64
#define N3C 1152
#define Mm  16384

typedef __attribute__((ext_vector_type(8))) short bf16x8;
typedef __attribute__((ext_vector_type(4))) float f32x4;

#define MFMA16(a, b, c) __builtin_amdgcn_mfma_f32_16x16x32_bf16((a), (b), (c), 0, 0, 0)

__device__ __forceinline__ ushort f2bf(float f) {
    uint u = __float_as_uint(f);
    u += 0x7fff + ((u >> 16) & 1);          // RNE
    return (ushort)(u >> 16);
}
__device__ __forceinline__ float bf2f(ushort h) {
    return __uint_as_float(((uint)h) << 16);
}
__device__ __forceinline__ uint cvtpk(float lo, float hi) {
    uint r;
    asm("v_cvt_pk_bf16_f32 %0, %1, %2" : "=v"(r) : "v"(lo), "v"(hi));
    return r;
}
__device__ __forceinline__ void gll16(const void* g, void* l) {
    __builtin_amdgcn_global_load_lds(
        (const __attribute__((address_space(1))) void*)g,
        (__attribute__((address_space(3))) void*)l, 16, 0, 0);
}

// ---------------- RoPE table ----------------
__global__ void rope_table_k(float* __restrict__ cosT, float* __restrict__ sinT) {
    int idx = blockIdx.x * 256 + threadIdx.x;   // 8192 total
    int t = idx >> 5;
    int i = idx & 31;
    float inv = powf(10000.0f, -(float)i / 32.0f);
    float ang = (float)t * inv;
    cosT[idx] = cosf(ang);
    sinT[idx] = sinf(ang);
}

// ---------------- x -> bf16 hi/lo split ----------------
__global__ __launch_bounds__(256)
void cvt_x_k(const float* __restrict__ x, ushort* __restrict__ Xh,
             ushort* __restrict__ Xl) {
    int i = (blockIdx.x * 256 + threadIdx.x) * 4;
    float4 v = *(const float4*)&x[i];
    float vv[4] = {v.x, v.y, v.z, v.w};
    ushort h[4], l[4];
#pragma unroll
    for (int j = 0; j < 4; ++j) {
        h[j] = f2bf(vv[j]);
        l[j] = f2bf(vv[j] - bf2f(h[j]));
    }
    *(uint2*)&Xh[i] = *(uint2*)h;
    *(uint2*)&Xl[i] = *(uint2*)l;
}

// ---------------- weight transpose + hi/lo split ----------------
__global__ __launch_bounds__(256)
void cvt_w_k(const float* __restrict__ w, ushort* __restrict__ Wth,
             ushort* __restrict__ Wtl, int N, int K) {
    int nl = threadIdx.x & 63, kb = threadIdx.x >> 6;
    int n  = blockIdx.x * 64 + nl;
    int k0 = blockIdx.y * 64 + kb * 16;
    ushort h[16], l[16];
#pragma unroll
    for (int j = 0; j < 16; ++j) {
        float v = w[(size_t)(k0 + j) * N + n];
        h[j] = f2bf(v);
        l[j] = f2bf(v - bf2f(h[j]));
    }
    size_t o = (size_t)n * K + k0;
    *(uint4*)&Wth[o]     = *(uint4*)&h[0];
    *(uint4*)&Wth[o + 8] = *(uint4*)&h[8];
    *(uint4*)&Wtl[o]     = *(uint4*)&l[0];
    *(uint4*)&Wtl[o + 8] = *(uint4*)&l[8];
}

// ---------------- split-bf16 MFMA GEMM ----------------
// Per-wave tile (16*MF) x 64; waves WR x WC; block tile (16*MF*WR) x (64*WC).
// WC must be 2 (BN = 128). Single-buffered LDS, global_load_lds width=16,
// seg^(row&3) involution swizzle (global pre-swizzle + read XOR).
template<bool ROPE, int MF, int WR, int WC>
__global__ __launch_bounds__(WR * WC * 64, (WR * WC > 2) ? 2 : 4)
void mfma_gemm_k(const ushort* __restrict__ Ah, const ushort* __restrict__ Al,
                 const ushort* __restrict__ Bth, const ushort* __restrict__ Btl,
                 int N, int K,
                 const float* __restrict__ cosT, const float* __restrict__ sinT,
                 ushort* __restrict__ Qh, ushort* __restrict__ Ql,
                 ushort* __restrict__ Kh, ushort* __restrict__ Kl,
                 ushort* __restrict__ Vth, ushort* __restrict__ Vtl,
                 float* __restrict__ outC)
{
    constexpr int AM  = MF * 16 * WR;        // A rows per block
    constexpr int CA  = AM / 16;             // 1KB chunks per A array
    constexpr int TOT = 2 * CA + 16;         // total chunks per K-step
    constexpr int CPW = TOT / (WR * WC);     // chunks per wave

    __shared__ ushort sAh[AM * 32], sAl[AM * 32];
    __shared__ ushort sBh[4096],    sBl[4096];

    const int tid  = threadIdx.x;
    const int lane = tid & 63;
    const int wid  = tid >> 6;
    const int wm   = wid / WC, wn = wid % WC;
    const int q16  = lane & 15;
    const int g    = lane >> 4;

    // XCD-swizzled 1-D block decode (gridDim % 8 == 0, bijective)
    const int nbx = N >> 7;
    const int xcd = blockIdx.x & 7;
    const int s   = blockIdx.x >> 3;
    const int mpx = (int)(gridDim.x >> 3) / nbx;
    const int m0  = (xcd * mpx + s / nbx) * AM;
    const int n0  = (s % nbx) << 7;

    // per-lane staging offsets (row within chunk, swizzled 16B segment)
    const int srow = lane >> 2;
    const int sseg = ((lane & 3) ^ (srow & 3)) * 8;

    f32x4 acc[MF][4];
#pragma unroll
    for (int i = 0; i < MF; ++i)
#pragma unroll
        for (int j = 0; j < 4; ++j) acc[i][j] = (f32x4){0.f, 0.f, 0.f, 0.f};

    const int kswz = ((g ^ (q16 & 3)) * 8);
    const int rA = wm * (16 * MF) + q16;
    const int rB = wn * 64 + q16;

    for (int kc = 0; kc < K; kc += 32) {
        __syncthreads();                     // prev tile fully consumed
#pragma unroll
        for (int j = 0; j < CPW; ++j) {
            const int c = CPW * wid + j;
            const ushort* gp; ushort* lp; int idx, r0;
            if (c < CA)            { gp = Ah;  lp = sAh; idx = c;          r0 = m0; }
            else if (c < 2*CA)     { gp = Al;  lp = sAl; idx = c - CA;     r0 = m0; }
            else if (c < 2*CA + 8) { gp = Bth; lp = sBh; idx = c - 2*CA;   r0 = n0; }
            else                   { gp = Btl; lp = sBl; idx = c - 2*CA-8; r0 = n0; }
            gll16(gp + (size_t)(r0 + idx*16 + srow) * K + sseg + kc,
                  lp + idx * 512);
        }
        asm volatile("s_waitcnt vmcnt(0)" ::: "memory");
        __syncthreads();                     // tile staged

        bf16x8 fa_h[MF], fa_l[MF];
#pragma unroll
        for (int f = 0; f < MF; ++f) {
            fa_h[f] = *(const bf16x8*)&sAh[(rA + f*16)*32 + kswz];
            fa_l[f] = *(const bf16x8*)&sAl[(rA + f*16)*32 + kswz];
        }
#pragma unroll
        for (int fn = 0; fn < 4; ++fn) {
            bf16x8 fbh = *(const bf16x8*)&sBh[(rB + fn*16)*32 + kswz];
            bf16x8 fbl = *(const bf16x8*)&sBl[(rB + fn*16)*32 + kswz];
#pragma unroll
            for (int fm = 0; fm < MF; ++fm) {
                acc[fm][fn] = MFMA16(fa_h[fm], fbh, acc[fm][fn]);
                acc[fm][fn] = MFMA16(fa_h[fm], fbl, acc[fm][fn]);
                acc[fm][fn] = MFMA16(fa_l[fm], fbh, acc[fm][fn]);
            }
        }
    }

    if (ROPE) {
#pragma unroll
        for (int fn = 0; fn < 4; ++fn) {
            int nglob = n0 + wn*64 + fn*16 + q16;
            int which = nglob / Cc;                 // block-uniform
            int nloc  = nglob - which * Cc;
            int h = nloc >> 6, d = nloc & 63;
#pragma unroll
            for (int fm = 0; fm < MF; ++fm) {
                int mbase = m0 + wm*(16*MF) + fm*16 + (g << 2);
                int b = mbase >> 8, t0 = mbase & 255;
                int bh = b * NHh + h;
                if (which == 2) {
                    ushort hv[4], lv[4];
#pragma unroll
                    for (int r = 0; r < 4; ++r) {
                        float v = acc[fm][fn][r];
                        hv[r] = f2bf(v);
                        lv[r] = f2bf(v - bf2f(hv[r]));
                    }
                    size_t o = ((size_t)bh * HDd + d) * Tt + t0;
                    *(uint2*)&Vth[o] = *(uint2*)hv;
                    *(uint2*)&Vtl[o] = *(uint2*)lv;
                } else {
#pragma unroll
                    for (int r = 0; r < 4; ++r) {
                        int t = t0 + r;
                        float v = acc[fm][fn][r];
                        float part = __shfl_xor(v, 1);
                        float cs = cosT[t*32 + (d >> 1)];
                        float sn = sinT[t*32 + (d >> 1)];
                        float nv = (d & 1) ? fmaf(v, cs,  part * sn)
                                           : fmaf(v, cs, -part * sn);
                        if (which == 0) nv *= 0.125f;
                        ushort hv = f2bf(nv);
                        ushort lv = f2bf(nv - bf2f(hv));
                        size_t o = ((size_t)bh * Tt + t) * HDd + d;
                        if (which == 0) { Qh[o] = hv; Ql[o] = lv; }
                        else            { Kh[o] = hv; Kl[o] = lv; }
                    }
                }
            }
        }
    } else {
#pragma unroll
        for (int fm = 0; fm < MF; ++fm)
#pragma unroll
            for (int fn = 0; fn < 4; ++fn) {
                int nglob = n0 + wn*64 + fn*16 + q16;
#pragma unroll
                for (int r = 0; r < 4; ++r) {
                    int m = m0 + wm*(16*MF) + fm*16 + (g << 2) + r;
                    outC[(size_t)m * N + nglob] = acc[fm][fn][r];
                }
            }
    }
}

// ---------------- MFMA flash attention, causal, split-bf16 ----------------
__global__ __launch_bounds__(256, 3)
void attn_mfma_k(const ushort* __restrict__ Qh, const ushort* __restrict__ Ql,
                 const ushort* __restrict__ Kh, const ushort* __restrict__ Kl,
                 const ushort* __restrict__ Vth, const ushort* __restrict__ Vtl,
                 ushort* __restrict__ AOh, ushort* __restrict__ AOl)
{
    __shared__ ushort sP[4][2][512];        // [wave][hi/lo][16q x 32key] = 8KB
    const int e    = blockIdx.x & 1;
    const int bh   = blockIdx.x >> 1;
    const int wid  = threadIdx.x >> 6;
    const int lane = threadIdx.x & 63;
    const int q16  = lane & 15;
    const int g    = lane >> 4;

    const int b = bh / NHh, h = bh % NHh;
    char* pbh = (char*)&sP[wid][0][0];
    char* pbl = (char*)&sP[wid][1][0];
    const int xorq = (q16 & 3) << 4;

    const size_t qkbase = (size_t)bh * Tt * HDd;
    const size_t vtbase = (size_t)bh * HDd * Tt;

#pragma unroll
    for (int ti = 0; ti < 2; ++ti) {
        const int tile  = ti == 0 ? (e + 2*wid) : (e + 14 - 2*wid);
        const int qbase = tile * 16;
        const int nch   = (tile >> 1) + 1;

        bf16x8 fqh[2], fql[2];
        {
            const size_t qo = qkbase + (size_t)(qbase + q16) * HDd + 8*g;
            fqh[0] = *(const bf16x8*)&Qh[qo];
            fqh[1] = *(const bf16x8*)&Qh[qo + 32];
            fql[0] = *(const bf16x8*)&Ql[qo];
            fql[1] = *(const bf16x8*)&Ql[qo + 32];
        }
        f32x4 acc[4];
#pragma unroll
        for (int dt = 0; dt < 4; ++dt) acc[dt] = (f32x4){0.f, 0.f, 0.f, 0.f};
        float mx = -1e30f, lsum = 0.f;

        for (int c = 0; c < nch; ++c) {
            const int kb = c * 32;
            f32x4 S[2];
#pragma unroll
            for (int kt = 0; kt < 2; ++kt) {
                const size_t ko = qkbase + (size_t)(kb + 16*kt + q16) * HDd + 8*g;
                bf16x8 kh0 = *(const bf16x8*)&Kh[ko];
                bf16x8 kh1 = *(const bf16x8*)&Kh[ko + 32];
                bf16x8 kl0 = *(const bf16x8*)&Kl[ko];
                bf16x8 kl1 = *(const bf16x8*)&Kl[ko + 32];
                f32x4 s = (f32x4){0.f, 0.f, 0.f, 0.f};
                s = MFMA16(kh0, fqh[0], s);
                s = MFMA16(kh0, fql[0], s);
                s = MFMA16(kl0, fqh[0], s);
                s = MFMA16(kh1, fqh[1], s);
                s = MFMA16(kh1, fql[1], s);
                s = MFMA16(kl1, fqh[1], s);
                S[kt] = s;
            }
            const int q = qbase + q16;
#pragma unroll
            for (int kt = 0; kt < 2; ++kt)
#pragma unroll
                for (int r = 0; r < 4; ++r) {
                    int key = kb + 16*kt + 4*g + r;
                    S[kt][r] = (key <= q) ? S[kt][r] : -1e30f;
                }
            float pm = fmaxf(fmaxf(fmaxf(S[0][0], S[0][1]), fmaxf(S[0][2], S[0][3])),
                             fmaxf(fmaxf(S[1][0], S[1][1]), fmaxf(S[1][2], S[1][3])));
            pm = fmaxf(pm, __shfl_xor(pm, 16));
            pm = fmaxf(pm, __shfl_xor(pm, 32));
            float nm   = fmaxf(mx, pm);
            float resc = __expf(mx - nm);
            mx = nm;

            float p[2][4];
            float csum = 0.f;
#pragma unroll
            for (int kt = 0; kt < 2; ++kt)
#pragma unroll
                for (int r = 0; r < 4; ++r) {
                    p[kt][r] = __expf(S[kt][r] - nm);
                    csum += p[kt][r];
                }
            csum += __shfl_xor(csum, 16);
            csum += __shfl_xor(csum, 32);
            lsum = lsum * resc + csum;

            float rs[4];
#pragma unroll
            for (int r = 0; r < 4; ++r) rs[r] = __shfl(resc, 4*g + r);
#pragma unroll
            for (int dt = 0; dt < 4; ++dt)
#pragma unroll
                for (int r = 0; r < 4; ++r) acc[dt][r] *= rs[r];

#pragma unroll
            for (int kt = 0; kt < 2; ++kt) {
                uint a0 = cvtpk(p[kt][0], p[kt][1]);
                uint a1 = cvtpk(p[kt][2], p[kt][3]);
                float e0 = p[kt][0] - __uint_as_float(a0 << 16);
                float e1 = p[kt][1] - __uint_as_float(a0 & 0xffff0000u);
                float e2 = p[kt][2] - __uint_as_float(a1 << 16);
                float e3 = p[kt][3] - __uint_as_float(a1 & 0xffff0000u);
                uint b0 = cvtpk(e0, e1);
                uint b1 = cvtpk(e2, e3);
                int off = q16 * 64 + ((32*kt + 8*g) ^ xorq);
                *(uint2*)(pbh + off) = (uint2){a0, a1};
                *(uint2*)(pbl + off) = (uint2){b0, b1};
            }
            const int roff = q16 * 64 + ((16*g) ^ xorq);
            bf16x8 pah = *(const bf16x8*)(pbh + roff);
            bf16x8 pal = *(const bf16x8*)(pbl + roff);

#pragma unroll
            for (int dt = 0; dt < 4; ++dt) {
                const size_t vo = vtbase + (size_t)(16*dt + q16) * Tt + kb + 8*g;
                bf16x8 vh = *(const bf16x8*)&Vth[vo];
                bf16x8 vl = *(const bf16x8*)&Vtl[vo];
                acc[dt] = MFMA16(pah, vh, acc[dt]);
                acc[dt] = MFMA16(pah, vl, acc[dt]);
                acc[dt] = MFMA16(pal, vh, acc[dt]);
            }
        }

        float il[4];
#pragma unroll
        for (int r = 0; r < 4; ++r) il[r] = 1.0f / __shfl(lsum, 4*g + r);
#pragma unroll
        for (int dt = 0; dt < 4; ++dt) {
            int d = 16*dt + q16;
#pragma unroll
            for (int r = 0; r < 4; ++r) {
                int q = qbase + 4*g + r;
                float o = acc[dt][r] * il[r];
                ushort oh = f2bf(o);
                ushort ol = f2bf(o - bf2f(oh));
                size_t oo = ((size_t)(b * Tt + q)) * Cc + h * HDd + d;
                AOh[oo] = oh;
                AOl[oo] = ol;
            }
        }
    }
}

// ---------------- launcher ----------------
extern "C" void kernel_launch(void* const* d_in, const int* in_sizes, int n_in,
                              void* d_out, int out_size, void* d_ws, size_t ws_size,
                              hipStream_t stream) {
    (void)in_sizes; (void)n_in; (void)out_size; (void)ws_size;
    const float* x      = (const float*)d_in[0];
    const float* w_attn = (const float*)d_in[1];
    const float* w_proj = (const float*)d_in[2];
    float* out = (float*)d_out;

    const size_t SZ = (size_t)Bb * NHh * Tt * HDd;   // 6,291,456
    char* base = (char*)d_ws;
    float*  cosT = (float*)base;
    float*  sinT = cosT + 8192;
    ushort* Qh   = (ushort*)(base + 65536);
    ushort* Ql   = Qh + SZ;
    ushort* Kh   = Ql + SZ;
    ushort* Kl   = Kh + SZ;
    ushort* Vth  = Kl + SZ;
    ushort* Vtl  = Vth + SZ;
    ushort* Xh   = Vtl + SZ;
    ushort* Xl   = Xh + SZ;
    ushort* AOh  = Xh;                // alias: X dead after QKV GEMM
    ushort* AOl  = Xl;
    ushort* Wath = Xl + SZ;
    ushort* Watl = Wath + (size_t)N3C * Cc;
    ushort* Wph  = Watl + (size_t)N3C * Cc;
    ushort* Wpl  = Wph  + (size_t)Cc * Cc;

    hipLaunchKernelGGL(rope_table_k, dim3(32), dim3(256), 0, stream, cosT, sinT);
    hipLaunchKernelGGL(cvt_x_k, dim3(Mm * Cc / 1024), dim3(256), 0, stream,
                       x, Xh, Xl);
    hipLaunchKernelGGL(cvt_w_k, dim3(N3C / 64, Cc / 64), dim3(256), 0, stream,
                       w_attn, Wath, Watl, N3C, Cc);
    hipLaunchKernelGGL(cvt_w_k, dim3(Cc / 64, Cc / 64), dim3(256), 0, stream,
                       w_proj, Wph, Wpl, Cc, Cc);

    // QKV: 256x128 tile, 4 waves, MF=8 -> grid 64*9 = 576 (div by 8)
    hipLaunchKernelGGL((mfma_gemm_k<true, 8, 2, 2>),
                       dim3((Mm / 256) * (N3C / 128)), dim3(256), 0, stream,
                       Xh, Xl, Wath, Watl, N3C, Cc,
                       cosT, sinT, Qh, Ql, Kh, Kl, Vth, Vtl, (float*)nullptr);

    hipLaunchKernelGGL(attn_mfma_k, dim3(Bb * NHh * 2), dim3(256), 0, stream,
                       Qh, Ql, Kh, Kl, Vth, Vtl, AOh, AOl);

    // proj: 64x128 tile, 2 waves, MF=4 -> grid 256*3 = 768 (div by 8)
    hipLaunchKernelGGL((mfma_gemm_k<false, 4, 1, 2>),
                       dim3((Mm / 64) * (Cc / 128)), dim3(128), 0, stream,
                       AOh, AOl, Wph, Wpl, Cc, Cc,
                       (const float*)nullptr, (const float*)nullptr,
                       (ushort*)nullptr, (ushort*)nullptr, (ushort*)nullptr,
                       (ushort*)nullptr, (ushort*)nullptr, (ushort*)nullptr, out);
}

// Round 8
// 241.929 us; speedup vs baseline: 1.0545x; 1.0545x over previous
//
#include <hip/hip_runtime.h>
#include <math.h>

#define Bb  64
#define Tt  256
#define Cc  384
#define NHh 6
#define HDd 64
#define N3C 1152
#define Mm  16384

typedef __attribute__((ext_vector_type(8))) short bf16x8;
typedef __attribute__((ext_vector_type(4))) float f32x4;

#define MFMA16(a, b, c) __builtin_amdgcn_mfma_f32_16x16x32_bf16((a), (b), (c), 0, 0, 0)

__device__ __forceinline__ ushort f2bf(float f) {
    uint u = __float_as_uint(f);
    u += 0x7fff + ((u >> 16) & 1);          // RNE
    return (ushort)(u >> 16);
}
__device__ __forceinline__ float bf2f(ushort h) {
    return __uint_as_float(((uint)h) << 16);
}
__device__ __forceinline__ uint cvtpk(float lo, float hi) {
    uint r;
    asm("v_cvt_pk_bf16_f32 %0, %1, %2" : "=v"(r) : "v"(lo), "v"(hi));
    return r;
}
__device__ __forceinline__ void gll16(const void* g, void* l) {
    __builtin_amdgcn_global_load_lds(
        (const __attribute__((address_space(1))) void*)g,
        (__attribute__((address_space(3))) void*)l, 16, 0, 0);
}
#define SBAR()                                  \
    do {                                        \
        __builtin_amdgcn_sched_barrier(0);      \
        __builtin_amdgcn_s_barrier();           \
        __builtin_amdgcn_sched_barrier(0);      \
    } while (0)

// ---------------- RoPE table ----------------
__global__ void rope_table_k(float* __restrict__ cosT, float* __restrict__ sinT) {
    int idx = blockIdx.x * 256 + threadIdx.x;   // 8192 total
    int t = idx >> 5;
    int i = idx & 31;
    float inv = powf(10000.0f, -(float)i / 32.0f);
    float ang = (float)t * inv;
    cosT[idx] = cosf(ang);
    sinT[idx] = sinf(ang);
}

// ---------------- x -> bf16 hi/lo split ----------------
__global__ __launch_bounds__(256)
void cvt_x_k(const float* __restrict__ x, ushort* __restrict__ Xh,
             ushort* __restrict__ Xl) {
    int i = (blockIdx.x * 256 + threadIdx.x) * 4;
    float4 v = *(const float4*)&x[i];
    float vv[4] = {v.x, v.y, v.z, v.w};
    ushort h[4], l[4];
#pragma unroll
    for (int j = 0; j < 4; ++j) {
        h[j] = f2bf(vv[j]);
        l[j] = f2bf(vv[j] - bf2f(h[j]));
    }
    *(uint2*)&Xh[i] = *(uint2*)h;
    *(uint2*)&Xl[i] = *(uint2*)l;
}

// ---------------- weight transpose + hi/lo split ----------------
__global__ __launch_bounds__(256)
void cvt_w_k(const float* __restrict__ w, ushort* __restrict__ Wth,
             ushort* __restrict__ Wtl, int N, int K) {
    int nl = threadIdx.x & 63, kb = threadIdx.x >> 6;
    int n  = blockIdx.x * 64 + nl;
    int k0 = blockIdx.y * 64 + kb * 16;
    ushort h[16], l[16];
#pragma unroll
    for (int j = 0; j < 16; ++j) {
        float v = w[(size_t)(k0 + j) * N + n];
        h[j] = f2bf(v);
        l[j] = f2bf(v - bf2f(h[j]));
    }
    size_t o = (size_t)n * K + k0;
    *(uint4*)&Wth[o]     = *(uint4*)&h[0];
    *(uint4*)&Wth[o + 8] = *(uint4*)&h[8];
    *(uint4*)&Wtl[o]     = *(uint4*)&l[0];
    *(uint4*)&Wtl[o + 8] = *(uint4*)&l[8];
}

// ---------------- split-bf16 MFMA GEMM, 2-deep sub-tile pipeline --------
// 128x128 tile, 4 waves (2x2), ring-2 over 32-k sub-tiles:
//   read frags(buf) -> lgkm0 -> barrier -> STAGE(sub+2 -> buf) -> MFMA
//   -> vmcnt(8) -> barrier
// Counted vmcnt keeps next sub's loads in flight across barriers (T3/T4).
template<bool ROPE>
__global__ __launch_bounds__(256)
void mfma_gemm_k(const ushort* __restrict__ Ah, const ushort* __restrict__ Al,
                 const ushort* __restrict__ Bth, const ushort* __restrict__ Btl,
                 int N, int K,
                 const float* __restrict__ cosT, const float* __restrict__ sinT,
                 ushort* __restrict__ Qh, ushort* __restrict__ Ql,
                 ushort* __restrict__ Kh, ushort* __restrict__ Kl,
                 ushort* __restrict__ Vth, ushort* __restrict__ Vtl,
                 float* __restrict__ outC)
{
    __shared__ ushort sAh[2][4096], sAl[2][4096], sBh[2][4096], sBl[2][4096];
    const int tid  = threadIdx.x;
    const int lane = tid & 63;
    const int wid  = tid >> 6;
    const int wm   = wid >> 1, wn = wid & 1;
    const int q16  = lane & 15;
    const int g    = lane >> 4;

    // XCD-swizzled 1-D block decode (gridDim % 8 == 0, bijective)
    const int nbx = N >> 7;
    const int xcd = blockIdx.x & 7;
    const int sb  = blockIdx.x >> 3;
    const int mpx = (int)(gridDim.x >> 3) / nbx;
    const int m0  = (xcd * mpx + sb / nbx) << 7;
    const int n0  = (sb % nbx) << 7;

    // per-lane staging offsets (row within 16-row chunk, swizzled 16B seg)
    const int srow = lane >> 2;
    const int sseg = ((lane & 3) ^ (srow & 3)) * 8;

    // wave's staging array (one array per wave, 8 chunks per sub-tile)
    const ushort* gp = (wid == 0) ? Ah : (wid == 1) ? Al
                      : (wid == 2) ? Bth : Btl;
    ushort* lp = (wid == 0) ? &sAh[0][0] : (wid == 1) ? &sAl[0][0]
                : (wid == 2) ? &sBh[0][0] : &sBl[0][0];
    const int r0 = (wid < 2) ? m0 : n0;
    const ushort* gw = gp + (size_t)(r0 + srow) * K + sseg;

#define STAGE_SUB(sub, buf)                                                   \
    {                                                                         \
        _Pragma("unroll")                                                     \
        for (int j = 0; j < 8; ++j)                                           \
            gll16(gw + (size_t)j * 16 * K + (sub) * 32,                       \
                  lp + (buf) * 4096 + j * 512);                               \
    }

    f32x4 acc[4][4];
#pragma unroll
    for (int i = 0; i < 4; ++i)
#pragma unroll
        for (int j = 0; j < 4; ++j) acc[i][j] = (f32x4){0.f, 0.f, 0.f, 0.f};

    const int kswz = ((g ^ (q16 & 3)) * 8);
    const int rA = wm * 64 + q16;
    const int rB = wn * 64 + q16;
    const int nsub = K >> 5;

    STAGE_SUB(0, 0)
    STAGE_SUB(1, 1)
    asm volatile("s_waitcnt vmcnt(8)" ::: "memory");   // sub0 landed
    SBAR();

    for (int s = 0; s < nsub; ++s) {
        const int buf = s & 1;
        bf16x8 fa_h[4], fa_l[4], fb_h[4], fb_l[4];
#pragma unroll
        for (int f = 0; f < 4; ++f) {
            fa_h[f] = *(const bf16x8*)&sAh[buf][(rA + f*16)*32 + kswz];
            fa_l[f] = *(const bf16x8*)&sAl[buf][(rA + f*16)*32 + kswz];
            fb_h[f] = *(const bf16x8*)&sBh[buf][(rB + f*16)*32 + kswz];
            fb_l[f] = *(const bf16x8*)&sBl[buf][(rB + f*16)*32 + kswz];
        }
        asm volatile("s_waitcnt lgkmcnt(0)" ::: "memory");  // my reads done
        SBAR();                                             // buffer free

        if (s + 2 < nsub) STAGE_SUB(s + 2, buf)

#pragma unroll
        for (int fm = 0; fm < 4; ++fm)
#pragma unroll
            for (int fn = 0; fn < 4; ++fn) {
                acc[fm][fn] = MFMA16(fa_h[fm], fb_h[fn], acc[fm][fn]);
                acc[fm][fn] = MFMA16(fa_h[fm], fb_l[fn], acc[fm][fn]);
                acc[fm][fn] = MFMA16(fa_l[fm], fb_h[fn], acc[fm][fn]);
            }

        if (s + 2 < nsub)
            asm volatile("s_waitcnt vmcnt(8)" ::: "memory");  // sub s+1 in
        else
            asm volatile("s_waitcnt vmcnt(0)" ::: "memory");  // drain tail
        SBAR();
    }
#undef STAGE_SUB

    if (ROPE) {
#pragma unroll
        for (int fn = 0; fn < 4; ++fn) {
            int nglob = n0 + wn*64 + fn*16 + q16;
            int which = nglob / Cc;                 // block-uniform
            int nloc  = nglob - which * Cc;
            int h = nloc >> 6, d = nloc & 63;
#pragma unroll
            for (int fm = 0; fm < 4; ++fm) {
                int mbase = m0 + wm*64 + fm*16 + (g << 2);
                int b = mbase >> 8, t0 = mbase & 255;
                int bh = b * NHh + h;
                if (which == 2) {
                    ushort hv[4], lv[4];
#pragma unroll
                    for (int r = 0; r < 4; ++r) {
                        float v = acc[fm][fn][r];
                        hv[r] = f2bf(v);
                        lv[r] = f2bf(v - bf2f(hv[r]));
                    }
                    size_t o = ((size_t)bh * HDd + d) * Tt + t0;
                    *(uint2*)&Vth[o] = *(uint2*)hv;
                    *(uint2*)&Vtl[o] = *(uint2*)lv;
                } else {
#pragma unroll
                    for (int r = 0; r < 4; ++r) {
                        int t = t0 + r;
                        float v = acc[fm][fn][r];
                        float part = __shfl_xor(v, 1);
                        float cs = cosT[t*32 + (d >> 1)];
                        float sn = sinT[t*32 + (d >> 1)];
                        float nv = (d & 1) ? fmaf(v, cs,  part * sn)
                                           : fmaf(v, cs, -part * sn);
                        if (which == 0) nv *= 0.125f;
                        ushort hv = f2bf(nv);
                        ushort lv = f2bf(nv - bf2f(hv));
                        size_t o = ((size_t)bh * Tt + t) * HDd + d;
                        if (which == 0) { Qh[o] = hv; Ql[o] = lv; }
                        else            { Kh[o] = hv; Kl[o] = lv; }
                    }
                }
            }
        }
    } else {
#pragma unroll
        for (int fm = 0; fm < 4; ++fm)
#pragma unroll
            for (int fn = 0; fn < 4; ++fn) {
                int nglob = n0 + wn*64 + fn*16 + q16;
#pragma unroll
                for (int r = 0; r < 4; ++r) {
                    int m = m0 + wm*64 + fm*16 + (g << 2) + r;
                    outC[(size_t)m * N + nglob] = acc[fm][fn][r];
                }
            }
    }
}

// ---------------- MFMA flash attention, causal, split-bf16 ----------------
__global__ __launch_bounds__(256, 3)
void attn_mfma_k(const ushort* __restrict__ Qh, const ushort* __restrict__ Ql,
                 const ushort* __restrict__ Kh, const ushort* __restrict__ Kl,
                 const ushort* __restrict__ Vth, const ushort* __restrict__ Vtl,
                 ushort* __restrict__ AOh, ushort* __restrict__ AOl)
{
    __shared__ ushort sP[4][2][512];        // [wave][hi/lo][16q x 32key] = 8KB
    const int e    = blockIdx.x & 1;
    const int bh   = blockIdx.x >> 1;
    const int wid  = threadIdx.x >> 6;
    const int lane = threadIdx.x & 63;
    const int q16  = lane & 15;
    const int g    = lane >> 4;

    const int b = bh / NHh, h = bh % NHh;
    char* pbh = (char*)&sP[wid][0][0];
    char* pbl = (char*)&sP[wid][1][0];
    const int xorq = (q16 & 3) << 4;

    const size_t qkbase = (size_t)bh * Tt * HDd;
    const size_t vtbase = (size_t)bh * HDd * Tt;

#pragma unroll
    for (int ti = 0; ti < 2; ++ti) {
        const int tile  = ti == 0 ? (e + 2*wid) : (e + 14 - 2*wid);
        const int qbase = tile * 16;
        const int nch   = (tile >> 1) + 1;

        bf16x8 fqh[2], fql[2];
        {
            const size_t qo = qkbase + (size_t)(qbase + q16) * HDd + 8*g;
            fqh[0] = *(const bf16x8*)&Qh[qo];
            fqh[1] = *(const bf16x8*)&Qh[qo + 32];
            fql[0] = *(const bf16x8*)&Ql[qo];
            fql[1] = *(const bf16x8*)&Ql[qo + 32];
        }
        f32x4 acc[4];
#pragma unroll
        for (int dt = 0; dt < 4; ++dt) acc[dt] = (f32x4){0.f, 0.f, 0.f, 0.f};
        float mx = -1e30f, lsum = 0.f;

        for (int c = 0; c < nch; ++c) {
            const int kb = c * 32;
            f32x4 S[2];
#pragma unroll
            for (int kt = 0; kt < 2; ++kt) {
                const size_t ko = qkbase + (size_t)(kb + 16*kt + q16) * HDd + 8*g;
                bf16x8 kh0 = *(const bf16x8*)&Kh[ko];
                bf16x8 kh1 = *(const bf16x8*)&Kh[ko + 32];
                bf16x8 kl0 = *(const bf16x8*)&Kl[ko];
                bf16x8 kl1 = *(const bf16x8*)&Kl[ko + 32];
                f32x4 s = (f32x4){0.f, 0.f, 0.f, 0.f};
                s = MFMA16(kh0, fqh[0], s);
                s = MFMA16(kh0, fql[0], s);
                s = MFMA16(kl0, fqh[0], s);
                s = MFMA16(kh1, fqh[1], s);
                s = MFMA16(kh1, fql[1], s);
                s = MFMA16(kl1, fqh[1], s);
                S[kt] = s;
            }
            const int q = qbase + q16;
#pragma unroll
            for (int kt = 0; kt < 2; ++kt)
#pragma unroll
                for (int r = 0; r < 4; ++r) {
                    int key = kb + 16*kt + 4*g + r;
                    S[kt][r] = (key <= q) ? S[kt][r] : -1e30f;
                }
            float pm = fmaxf(fmaxf(fmaxf(S[0][0], S[0][1]), fmaxf(S[0][2], S[0][3])),
                             fmaxf(fmaxf(S[1][0], S[1][1]), fmaxf(S[1][2], S[1][3])));
            pm = fmaxf(pm, __shfl_xor(pm, 16));
            pm = fmaxf(pm, __shfl_xor(pm, 32));
            float nm   = fmaxf(mx, pm);
            float resc = __expf(mx - nm);
            mx = nm;

            float p[2][4];
            float csum = 0.f;
#pragma unroll
            for (int kt = 0; kt < 2; ++kt)
#pragma unroll
                for (int r = 0; r < 4; ++r) {
                    p[kt][r] = __expf(S[kt][r] - nm);
                    csum += p[kt][r];
                }
            csum += __shfl_xor(csum, 16);
            csum += __shfl_xor(csum, 32);
            lsum = lsum * resc + csum;

            float rs[4];
#pragma unroll
            for (int r = 0; r < 4; ++r) rs[r] = __shfl(resc, 4*g + r);
#pragma unroll
            for (int dt = 0; dt < 4; ++dt)
#pragma unroll
                for (int r = 0; r < 4; ++r) acc[dt][r] *= rs[r];

#pragma unroll
            for (int kt = 0; kt < 2; ++kt) {
                uint a0 = cvtpk(p[kt][0], p[kt][1]);
                uint a1 = cvtpk(p[kt][2], p[kt][3]);
                float e0 = p[kt][0] - __uint_as_float(a0 << 16);
                float e1 = p[kt][1] - __uint_as_float(a0 & 0xffff0000u);
                float e2 = p[kt][2] - __uint_as_float(a1 << 16);
                float e3 = p[kt][3] - __uint_as_float(a1 & 0xffff0000u);
                uint b0 = cvtpk(e0, e1);
                uint b1 = cvtpk(e2, e3);
                int off = q16 * 64 + ((32*kt + 8*g) ^ xorq);
                *(uint2*)(pbh + off) = (uint2){a0, a1};
                *(uint2*)(pbl + off) = (uint2){b0, b1};
            }
            const int roff = q16 * 64 + ((16*g) ^ xorq);
            bf16x8 pah = *(const bf16x8*)(pbh + roff);
            bf16x8 pal = *(const bf16x8*)(pbl + roff);

#pragma unroll
            for (int dt = 0; dt < 4; ++dt) {
                const size_t vo = vtbase + (size_t)(16*dt + q16) * Tt + kb + 8*g;
                bf16x8 vh = *(const bf16x8*)&Vth[vo];
                bf16x8 vl = *(const bf16x8*)&Vtl[vo];
                acc[dt] = MFMA16(pah, vh, acc[dt]);
                acc[dt] = MFMA16(pah, vl, acc[dt]);
                acc[dt] = MFMA16(pal, vh, acc[dt]);
            }
        }

        float il[4];
#pragma unroll
        for (int r = 0; r < 4; ++r) il[r] = 1.0f / __shfl(lsum, 4*g + r);
#pragma unroll
        for (int dt = 0; dt < 4; ++dt) {
            int d = 16*dt + q16;
#pragma unroll
            for (int r = 0; r < 4; ++r) {
                int q = qbase + 4*g + r;
                float o = acc[dt][r] * il[r];
                ushort oh = f2bf(o);
                ushort ol = f2bf(o - bf2f(oh));
                size_t oo = ((size_t)(b * Tt + q)) * Cc + h * HDd + d;
                AOh[oo] = oh;
                AOl[oo] = ol;
            }
        }
    }
}

// ---------------- launcher ----------------
extern "C" void kernel_launch(void* const* d_in, const int* in_sizes, int n_in,
                              void* d_out, int out_size, void* d_ws, size_t ws_size,
                              hipStream_t stream) {
    (void)in_sizes; (void)n_in; (void)out_size; (void)ws_size;
    const float* x      = (const float*)d_in[0];
    const float* w_attn = (const float*)d_in[1];
    const float* w_proj = (const float*)d_in[2];
    float* out = (float*)d_out;

    const size_t SZ = (size_t)Bb * NHh * Tt * HDd;   // 6,291,456
    char* base = (char*)d_ws;
    float*  cosT = (float*)base;
    float*  sinT = cosT + 8192;
    ushort* Qh   = (ushort*)(base + 65536);
    ushort* Ql   = Qh + SZ;
    ushort* Kh   = Ql + SZ;
    ushort* Kl   = Kh + SZ;
    ushort* Vth  = Kl + SZ;
    ushort* Vtl  = Vth + SZ;
    ushort* Xh   = Vtl + SZ;
    ushort* Xl   = Xh + SZ;
    ushort* AOh  = Xh;                // alias: X dead after QKV GEMM
    ushort* AOl  = Xl;
    ushort* Wath = Xl + SZ;
    ushort* Watl = Wath + (size_t)N3C * Cc;
    ushort* Wph  = Watl + (size_t)N3C * Cc;
    ushort* Wpl  = Wph  + (size_t)Cc * Cc;

    hipLaunchKernelGGL(rope_table_k, dim3(32), dim3(256), 0, stream, cosT, sinT);
    hipLaunchKernelGGL(cvt_x_k, dim3(Mm * Cc / 1024), dim3(256), 0, stream,
                       x, Xh, Xl);
    hipLaunchKernelGGL(cvt_w_k, dim3(N3C / 64, Cc / 64), dim3(256), 0, stream,
                       w_attn, Wath, Watl, N3C, Cc);
    hipLaunchKernelGGL(cvt_w_k, dim3(Cc / 64, Cc / 64), dim3(256), 0, stream,
                       w_proj, Wph, Wpl, Cc, Cc);

    // QKV: 128x128 tiles, grid 128*9 = 1152 (div by 8)
    hipLaunchKernelGGL((mfma_gemm_k<true>), dim3((Mm / 128) * (N3C / 128)),
                       dim3(256), 0, stream, Xh, Xl, Wath, Watl, N3C, Cc,
                       cosT, sinT, Qh, Ql, Kh, Kl, Vth, Vtl, (float*)nullptr);

    hipLaunchKernelGGL(attn_mfma_k, dim3(Bb * NHh * 2), dim3(256), 0, stream,
                       Qh, Ql, Kh, Kl, Vth, Vtl, AOh, AOl);

    // proj: 128x128 tiles, grid 128*3 = 384 (div by 8)
    hipLaunchKernelGGL((mfma_gemm_k<false>), dim3((Mm / 128) * (Cc / 128)),
                       dim3(256), 0, stream, AOh, AOl, Wph, Wpl, Cc, Cc,
                       (const float*)nullptr, (const float*)nullptr,
                       (ushort*)nullptr, (ushort*)nullptr, (ushort*)nullptr,
                       (ushort*)nullptr, (ushort*)nullptr, (ushort*)nullptr, out);
}

// Round 9
// 158.635 us; speedup vs baseline: 1.6081x; 1.5251x over previous
//
#include <hip/hip_runtime.h>
#include <math.h>

#define Bb  64
#define Tt  256
#define Cc  384
#define NHh 6
#define HDd 64
#define N3C 1152
#define Mm  16384

typedef _Float16 half8 __attribute__((ext_vector_type(8)));
typedef __attribute__((ext_vector_type(4))) float f32x4;

#define MFMAH(a, b, c) __builtin_amdgcn_mfma_f32_16x16x32_f16((a), (b), (c), 0, 0, 0)

__device__ __forceinline__ ushort f2h(float f) {
    union { _Float16 h; ushort u; } c; c.h = (_Float16)f; return c.u;
}
__device__ __forceinline__ uint pkh(float lo, float hi) {
    uint r;
    asm("v_cvt_pkrtz_f16_f32 %0, %1, %2" : "=v"(r) : "v"(lo), "v"(hi));
    return r;
}
__device__ __forceinline__ void gll16(const void* g, void* l) {
    __builtin_amdgcn_global_load_lds(
        (const __attribute__((address_space(1))) void*)g,
        (__attribute__((address_space(3))) void*)l, 16, 0, 0);
}
#define SBAR()                                  \
    do {                                        \
        __builtin_amdgcn_sched_barrier(0);      \
        __builtin_amdgcn_s_barrier();           \
        __builtin_amdgcn_sched_barrier(0);      \
    } while (0)

// ---------------- RoPE table ----------------
__global__ void rope_table_k(float* __restrict__ cosT, float* __restrict__ sinT) {
    int idx = blockIdx.x * 256 + threadIdx.x;   // 8192 total
    int t = idx >> 5;
    int i = idx & 31;
    float inv = powf(10000.0f, -(float)i / 32.0f);
    float ang = (float)t * inv;
    cosT[idx] = cosf(ang);
    sinT[idx] = sinf(ang);
}

// ---------------- x -> fp16 ----------------
__global__ __launch_bounds__(256)
void cvt_x_k(const float* __restrict__ x, ushort* __restrict__ Xf) {
    int i = (blockIdx.x * 256 + threadIdx.x) * 4;
    float4 v = *(const float4*)&x[i];
    ushort h[4] = {f2h(v.x), f2h(v.y), f2h(v.z), f2h(v.w)};
    *(uint2*)&Xf[i] = *(uint2*)h;
}

// ---------------- weight transpose + fp16: w[K][N] -> Wt[N][K] ----------
__global__ __launch_bounds__(256)
void cvt_w_k(const float* __restrict__ w, ushort* __restrict__ Wt, int N, int K) {
    int nl = threadIdx.x & 63, kb = threadIdx.x >> 6;
    int n  = blockIdx.x * 64 + nl;
    int k0 = blockIdx.y * 64 + kb * 16;
    ushort h[16];
#pragma unroll
    for (int j = 0; j < 16; ++j)
        h[j] = f2h(w[(size_t)(k0 + j) * N + n]);
    size_t o = (size_t)n * K + k0;
    *(uint4*)&Wt[o]     = *(uint4*)&h[0];
    *(uint4*)&Wt[o + 8] = *(uint4*)&h[8];
}

// ---------------- fp16 MFMA GEMM, 2-deep sub-tile ring ----------------
// 128x128 tile, 4 waves (2x2), BK=32, 1 MFMA per 16x16 tile.
// LDS: sA/sB double-buffered (32 KB). Staging via global_load_lds w=16,
// seg^(row&3) involution swizzle. Counted vmcnt(4) ring (T3/T4-lite).
template<bool ROPE>
__global__ __launch_bounds__(256, 4)
void mfma_gemm_k(const ushort* __restrict__ A, const ushort* __restrict__ Bt,
                 int N, int K,
                 const float* __restrict__ cosT, const float* __restrict__ sinT,
                 ushort* __restrict__ Qf, ushort* __restrict__ Kf,
                 ushort* __restrict__ Vtf, float* __restrict__ outC)
{
    __shared__ ushort sA[2][4096], sB[2][4096];
    const int tid  = threadIdx.x;
    const int lane = tid & 63;
    const int wid  = tid >> 6;
    const int wm   = wid >> 1, wn = wid & 1;
    const int q16  = lane & 15;
    const int g    = lane >> 4;

    // XCD-swizzled 1-D block decode (gridDim % 8 == 0, bijective)
    const int nbx = N >> 7;
    const int xcd = blockIdx.x & 7;
    const int sb  = blockIdx.x >> 3;
    const int mpx = (int)(gridDim.x >> 3) / nbx;
    const int m0  = (xcd * mpx + sb / nbx) << 7;
    const int n0  = (sb % nbx) << 7;

    // staging: wave owns 4 chunks (1 KB each). wid0/1 -> A, wid2/3 -> B.
    const int srow = lane >> 2;
    const int sseg = ((lane & 3) ^ (srow & 3)) * 8;
    const ushort* gp = (wid < 2) ? A : Bt;
    const int r0 = (wid < 2) ? m0 : n0;
    ushort* lp = ((wid < 2) ? &sA[0][0] : &sB[0][0]) + (wid & 1) * 2048;
    const ushort* gw = gp + (size_t)(r0 + (wid & 1) * 64 + srow) * K + sseg;

#define STAGE_SUB(sub, buf)                                                   \
    {                                                                         \
        _Pragma("unroll")                                                     \
        for (int j = 0; j < 4; ++j)                                           \
            gll16(gw + (size_t)j * 16 * K + (sub) * 32,                       \
                  lp + (buf) * 4096 + j * 512);                               \
    }

    f32x4 acc[4][4];
#pragma unroll
    for (int i = 0; i < 4; ++i)
#pragma unroll
        for (int j = 0; j < 4; ++j) acc[i][j] = (f32x4){0.f, 0.f, 0.f, 0.f};

    const int kswz = ((g ^ (q16 & 3)) * 8);
    const int rA = wm * 64 + q16;
    const int rB = wn * 64 + q16;
    const int nsub = K >> 5;

    STAGE_SUB(0, 0)
    STAGE_SUB(1, 1)
    asm volatile("s_waitcnt vmcnt(4)" ::: "memory");   // sub0 landed
    SBAR();

    for (int s = 0; s < nsub; ++s) {
        const int buf = s & 1;
        half8 fa[4], fb[4];
#pragma unroll
        for (int f = 0; f < 4; ++f) {
            fa[f] = *(const half8*)&sA[buf][(rA + f*16)*32 + kswz];
            fb[f] = *(const half8*)&sB[buf][(rB + f*16)*32 + kswz];
        }
        asm volatile("s_waitcnt lgkmcnt(0)" ::: "memory");
        SBAR();                                             // buffer free

        if (s + 2 < nsub) STAGE_SUB(s + 2, buf)

#pragma unroll
        for (int fm = 0; fm < 4; ++fm)
#pragma unroll
            for (int fn = 0; fn < 4; ++fn)
                acc[fm][fn] = MFMAH(fa[fm], fb[fn], acc[fm][fn]);

        if (s + 2 < nsub)
            asm volatile("s_waitcnt vmcnt(4)" ::: "memory");  // sub s+1 in
        else
            asm volatile("s_waitcnt vmcnt(0)" ::: "memory");
        SBAR();
    }
#undef STAGE_SUB

    if (ROPE) {
#pragma unroll
        for (int fn = 0; fn < 4; ++fn) {
            int nglob = n0 + wn*64 + fn*16 + q16;
            int which = nglob / Cc;                 // wave-uniform
            int nloc  = nglob - which * Cc;
            int h = nloc >> 6, d = nloc & 63;
#pragma unroll
            for (int fm = 0; fm < 4; ++fm) {
                int mbase = m0 + wm*64 + fm*16 + (g << 2);
                int b = mbase >> 8, t0 = mbase & 255;
                int bh = b * NHh + h;
                if (which == 2) {
                    ushort hv[4];
#pragma unroll
                    for (int r = 0; r < 4; ++r) hv[r] = f2h(acc[fm][fn][r]);
                    size_t o = ((size_t)bh * HDd + d) * Tt + t0;
                    *(uint2*)&Vtf[o] = *(uint2*)hv;
                } else {
#pragma unroll
                    for (int r = 0; r < 4; ++r) {
                        int t = t0 + r;
                        float v = acc[fm][fn][r];
                        float part = __shfl_xor(v, 1);
                        float cs = cosT[t*32 + (d >> 1)];
                        float sn = sinT[t*32 + (d >> 1)];
                        float nv = (d & 1) ? fmaf(v, cs,  part * sn)
                                           : fmaf(v, cs, -part * sn);
                        if (which == 0) nv *= 0.125f;
                        size_t o = ((size_t)bh * Tt + t) * HDd + d;
                        if (which == 0) Qf[o] = f2h(nv);
                        else            Kf[o] = f2h(nv);
                    }
                }
            }
        }
    } else {
#pragma unroll
        for (int fm = 0; fm < 4; ++fm)
#pragma unroll
            for (int fn = 0; fn < 4; ++fn) {
                int nglob = n0 + wn*64 + fn*16 + q16;
#pragma unroll
                for (int r = 0; r < 4; ++r) {
                    int m = m0 + wm*64 + fm*16 + (g << 2) + r;
                    outC[(size_t)m * N + nglob] = acc[fm][fn][r];
                }
            }
    }
}

// ---------------- fp16 MFMA flash attention, causal ----------------
// 8 MFMA per (q-tile, 32-key chunk): 4 QK^T + 4 PV (was 18 with split).
__global__ __launch_bounds__(256, 3)
void attn_mfma_k(const ushort* __restrict__ Qf, const ushort* __restrict__ Kf,
                 const ushort* __restrict__ Vtf, ushort* __restrict__ AOf)
{
    __shared__ ushort sP[4][512];           // [wave][16q x 32key] = 4KB
    const int e    = blockIdx.x & 1;
    const int bh   = blockIdx.x >> 1;
    const int wid  = threadIdx.x >> 6;
    const int lane = threadIdx.x & 63;
    const int q16  = lane & 15;
    const int g    = lane >> 4;

    const int b = bh / NHh, h = bh % NHh;
    char* pb = (char*)&sP[wid][0];
    const int xorq = (q16 & 3) << 4;

    const size_t qkbase = (size_t)bh * Tt * HDd;
    const size_t vtbase = (size_t)bh * HDd * Tt;

#pragma unroll
    for (int ti = 0; ti < 2; ++ti) {
        const int tile  = ti == 0 ? (e + 2*wid) : (e + 14 - 2*wid);
        const int qbase = tile * 16;
        const int nch   = (tile >> 1) + 1;

        half8 fq[2];
        {
            const size_t qo = qkbase + (size_t)(qbase + q16) * HDd + 8*g;
            fq[0] = *(const half8*)&Qf[qo];
            fq[1] = *(const half8*)&Qf[qo + 32];
        }
        f32x4 acc[4];
#pragma unroll
        for (int dt = 0; dt < 4; ++dt) acc[dt] = (f32x4){0.f, 0.f, 0.f, 0.f};
        float mx = -1e30f, lsum = 0.f;

        for (int c = 0; c < nch; ++c) {
            const int kb = c * 32;
            f32x4 S[2];
#pragma unroll
            for (int kt = 0; kt < 2; ++kt) {
                const size_t ko = qkbase + (size_t)(kb + 16*kt + q16) * HDd + 8*g;
                half8 k0 = *(const half8*)&Kf[ko];
                half8 k1 = *(const half8*)&Kf[ko + 32];
                f32x4 s = (f32x4){0.f, 0.f, 0.f, 0.f};
                s = MFMAH(k0, fq[0], s);
                s = MFMAH(k1, fq[1], s);
                S[kt] = s;
            }
            const int q = qbase + q16;
#pragma unroll
            for (int kt = 0; kt < 2; ++kt)
#pragma unroll
                for (int r = 0; r < 4; ++r) {
                    int key = kb + 16*kt + 4*g + r;
                    S[kt][r] = (key <= q) ? S[kt][r] : -1e30f;
                }
            float pm = fmaxf(fmaxf(fmaxf(S[0][0], S[0][1]), fmaxf(S[0][2], S[0][3])),
                             fmaxf(fmaxf(S[1][0], S[1][1]), fmaxf(S[1][2], S[1][3])));
            pm = fmaxf(pm, __shfl_xor(pm, 16));
            pm = fmaxf(pm, __shfl_xor(pm, 32));
            float nm   = fmaxf(mx, pm);
            float resc = __expf(mx - nm);
            mx = nm;

            float p[2][4];
            float csum = 0.f;
#pragma unroll
            for (int kt = 0; kt < 2; ++kt)
#pragma unroll
                for (int r = 0; r < 4; ++r) {
                    p[kt][r] = __expf(S[kt][r] - nm);
                    csum += p[kt][r];
                }
            csum += __shfl_xor(csum, 16);
            csum += __shfl_xor(csum, 32);
            lsum = lsum * resc + csum;

            float rs[4];
#pragma unroll
            for (int r = 0; r < 4; ++r) rs[r] = __shfl(resc, 4*g + r);
#pragma unroll
            for (int dt = 0; dt < 4; ++dt)
#pragma unroll
                for (int r = 0; r < 4; ++r) acc[dt][r] *= rs[r];

#pragma unroll
            for (int kt = 0; kt < 2; ++kt) {
                uint a0 = pkh(p[kt][0], p[kt][1]);
                uint a1 = pkh(p[kt][2], p[kt][3]);
                int off = q16 * 64 + ((32*kt + 8*g) ^ xorq);
                *(uint2*)(pb + off) = (uint2){a0, a1};
            }
            const int roff = q16 * 64 + ((16*g) ^ xorq);
            half8 pa = *(const half8*)(pb + roff);

#pragma unroll
            for (int dt = 0; dt < 4; ++dt) {
                const size_t vo = vtbase + (size_t)(16*dt + q16) * Tt + kb + 8*g;
                half8 vv = *(const half8*)&Vtf[vo];
                acc[dt] = MFMAH(pa, vv, acc[dt]);
            }
        }

        float il[4];
#pragma unroll
        for (int r = 0; r < 4; ++r) il[r] = 1.0f / __shfl(lsum, 4*g + r);
#pragma unroll
        for (int dt = 0; dt < 4; ++dt) {
            int d = 16*dt + q16;
#pragma unroll
            for (int r = 0; r < 4; ++r) {
                int q = qbase + 4*g + r;
                size_t oo = ((size_t)(b * Tt + q)) * Cc + h * HDd + d;
                AOf[oo] = f2h(acc[dt][r] * il[r]);
            }
        }
    }
}

// ---------------- launcher ----------------
extern "C" void kernel_launch(void* const* d_in, const int* in_sizes, int n_in,
                              void* d_out, int out_size, void* d_ws, size_t ws_size,
                              hipStream_t stream) {
    (void)in_sizes; (void)n_in; (void)out_size; (void)ws_size;
    const float* x      = (const float*)d_in[0];
    const float* w_attn = (const float*)d_in[1];
    const float* w_proj = (const float*)d_in[2];
    float* out = (float*)d_out;

    const size_t SZ = (size_t)Bb * NHh * Tt * HDd;   // 6,291,456
    char* base = (char*)d_ws;
    float*  cosT = (float*)base;
    float*  sinT = cosT + 8192;
    ushort* Qf   = (ushort*)(base + 65536);
    ushort* Kf   = Qf + SZ;
    ushort* Vtf  = Kf + SZ;
    ushort* Xf   = Vtf + SZ;
    ushort* AOf  = Xf;                // alias: X dead after QKV GEMM
    ushort* Watf = Xf + SZ;
    ushort* Wpf  = Watf + (size_t)N3C * Cc;

    hipLaunchKernelGGL(rope_table_k, dim3(32), dim3(256), 0, stream, cosT, sinT);
    hipLaunchKernelGGL(cvt_x_k, dim3(Mm * Cc / 1024), dim3(256), 0, stream,
                       x, Xf);
    hipLaunchKernelGGL(cvt_w_k, dim3(N3C / 64, Cc / 64), dim3(256), 0, stream,
                       w_attn, Watf, N3C, Cc);
    hipLaunchKernelGGL(cvt_w_k, dim3(Cc / 64, Cc / 64), dim3(256), 0, stream,
                       w_proj, Wpf, Cc, Cc);

    // QKV: 128x128 tiles, grid 128*9 = 1152 (div by 8)
    hipLaunchKernelGGL((mfma_gemm_k<true>), dim3((Mm / 128) * (N3C / 128)),
                       dim3(256), 0, stream, Xf, Watf, N3C, Cc,
                       cosT, sinT, Qf, Kf, Vtf, (float*)nullptr);

    hipLaunchKernelGGL(attn_mfma_k, dim3(Bb * NHh * 2), dim3(256), 0, stream,
                       Qf, Kf, Vtf, AOf);

    // proj: 128x128 tiles, grid 128*3 = 384 (div by 8)
    hipLaunchKernelGGL((mfma_gemm_k<false>), dim3((Mm / 128) * (Cc / 128)),
                       dim3(256), 0, stream, AOf, Wpf, Cc, Cc,
                       (const float*)nullptr, (const float*)nullptr,
                       (ushort*)nullptr, (ushort*)nullptr, (ushort*)nullptr, out);
}